// Round 1
// baseline (48994.510 us; speedup 1.0000x reference)
//
#include <hip/hip_runtime.h>
#include <hip/hip_bf16.h>

// RNN scan: T=1024, B=64, D_IN=1024, H=1024, fp32.
// out = [carry (64*1024)] ++ [outs (1024*64*1024)]
//
// Phase 1: xproj = xs @ Wih + bih  -> written into outs region of d_out.
// Phase 2: ONE persistent kernel (256 WGs = 1/CU), 1024 internal steps
//          separated by a device-scope atomic-counter barrier. Whh column
//          slice lives in LDS (loaded once). h_t lives in outs[t] (in-place
//          over xproj).

#define T_STEPS 1024
#define BATCH   64
#define HDIM    1024
#define NWG     256
#define NTHR    512

__device__ unsigned g_bar_fallback;

// ---------- small float4 helpers ----------
__device__ __forceinline__ float4 f4fma(float s, float4 v, float4 a) {
    a.x = fmaf(s, v.x, a.x);
    a.y = fmaf(s, v.y, a.y);
    a.z = fmaf(s, v.z, a.z);
    a.w = fmaf(s, v.w, a.w);
    return a;
}
__device__ __forceinline__ float4 f4add(float4 a, float4 b) {
    return make_float4(a.x + b.x, a.y + b.y, a.z + b.z, a.w + b.w);
}
__device__ __forceinline__ float fast_tanh(float x) {
    float ax = fabsf(x);
    float e  = __expf(2.0f * ax);          // v_exp_f32-based
    float r  = 1.0f - __fdividef(2.0f, e + 1.0f);
    return copysignf(r, x);
}

// ---------- Phase 1: xproj GEMM (fp32, 128x128 tile, 8x8 micro) ----------
// C[r, n] = sum_k A[r,k] * W[k,n] + bias[n];  M=65536, N=K=1024
__global__ __launch_bounds__(256) void xproj_gemm(
    const float* __restrict__ A,     // xs   [65536,1024]
    const float* __restrict__ W,     // Wih  [1024,1024]
    const float* __restrict__ bias,  // bih  [1024]
    float* __restrict__ C)           // outs [65536,1024]
{
    constexpr int K = 1024, N = 1024;
    __shared__ __align__(16) float As[8][132];
    __shared__ __align__(16) float Ws[8][132];

    const int tid = threadIdx.x;
    const int m0 = blockIdx.y * 128;
    const int n0 = blockIdx.x * 128;
    const int tx = tid & 15;          // 0..15 -> col groups
    const int ty = tid >> 4;          // 0..15 -> row groups

    const int arow = tid >> 1;            // 0..127
    const int kq   = (tid & 1) * 4;       // 0 or 4
    const int wrow = tid >> 5;            // 0..7
    const int wcol = (tid & 31) * 4;      // 0..124

    float4 c[2][4][2];
#pragma unroll
    for (int rb = 0; rb < 2; ++rb)
#pragma unroll
        for (int i = 0; i < 4; ++i)
#pragma unroll
            for (int cb = 0; cb < 2; ++cb)
                c[rb][i][cb] = make_float4(0.f, 0.f, 0.f, 0.f);

    for (int k0 = 0; k0 < K; k0 += 8) {
        float4 av = *(const float4*)(A + (size_t)(m0 + arow) * K + k0 + kq);
        float4 wv = *(const float4*)(W + (size_t)(k0 + wrow) * N + n0 + wcol);
        __syncthreads();
        As[kq + 0][arow] = av.x;
        As[kq + 1][arow] = av.y;
        As[kq + 2][arow] = av.z;
        As[kq + 3][arow] = av.w;
        *(float4*)&Ws[wrow][wcol] = wv;
        __syncthreads();
#pragma unroll
        for (int kk = 0; kk < 8; ++kk) {
            float4 a0 = *(const float4*)&As[kk][ty * 4];
            float4 a1 = *(const float4*)&As[kk][64 + ty * 4];
            float4 b0 = *(const float4*)&Ws[kk][tx * 4];
            float4 b1 = *(const float4*)&Ws[kk][64 + tx * 4];
            float a0a[4] = {a0.x, a0.y, a0.z, a0.w};
            float a1a[4] = {a1.x, a1.y, a1.z, a1.w};
#pragma unroll
            for (int i = 0; i < 4; ++i) {
                c[0][i][0] = f4fma(a0a[i], b0, c[0][i][0]);
                c[0][i][1] = f4fma(a0a[i], b1, c[0][i][1]);
                c[1][i][0] = f4fma(a1a[i], b0, c[1][i][0]);
                c[1][i][1] = f4fma(a1a[i], b1, c[1][i][1]);
            }
        }
    }

    float4 bv0 = *(const float4*)(bias + n0 + tx * 4);
    float4 bv1 = *(const float4*)(bias + n0 + 64 + tx * 4);
#pragma unroll
    for (int rb = 0; rb < 2; ++rb)
#pragma unroll
        for (int i = 0; i < 4; ++i) {
            int row = m0 + rb * 64 + ty * 4 + i;
            float* cp = C + (size_t)row * N + n0;
            *(float4*)(cp + tx * 4)      = f4add(c[rb][i][0], bv0);
            *(float4*)(cp + 64 + tx * 4) = f4add(c[rb][i][1], bv1);
        }
}

// ---------- Phase 2: persistent scan kernel ----------
// 256 WGs x 512 threads, 1 WG/CU. WG owns a 16-row x 16-col tile of h.
// Whh[:, jb..jb+15] lives in LDS as float4 quads along k (64 KB), loaded once.
// Per step: 8 waves split K (128 each); lane (rg,j) accumulates 4 rows x 1 col;
// LDS partial reduce across waves; wave ks finishes rows {2ks, 2ks+1}.
// Step barrier: release atomicAdd (flushes XCD L2) + relaxed spin +
// __threadfence (invalidate) -- manual version of the dispatch-boundary
// coherence the 1024-dispatch version relied on.
__global__ __launch_bounds__(NTHR) void rnn_scan_persistent(
    const float* __restrict__ Whh,    // [1024,1024]
    const float* __restrict__ bhh,    // [1024]
    const float* __restrict__ init,   // [64,1024]
    float* __restrict__ outs,         // [T][64][1024]  xproj in, h out
    float* __restrict__ carry,        // [64,1024]
    unsigned* __restrict__ bar)       // zeroed per replay
{
    __shared__ __align__(16) float4 Wl[256][16];   // Wl[kq][j] = W[4kq..4kq+3][jb+j]
    __shared__ float partf[8 * 16 * 17];           // [wave][row][17] (padded)

    const int tid  = threadIdx.x;
    const int lane = tid & 63;
    const int ks   = tid >> 6;          // wave 0..7: k-slice [ks*128, ks*128+128)
    const int rg   = lane >> 4;         // 0..3: row group (4 rows each)
    const int j    = lane & 15;         // column within tile

    // XCD-aware remap: the 32 WGs on one XCD share the same 16 h-rows.
    const int phys = blockIdx.x;
    const int l    = (phys & 7) * 32 + (phys >> 3);   // bijective, 256 % 8 == 0
    const int rbase = (l >> 6) * 16;    // 0,16,32,48
    const int jb    = (l & 63) * 16;    // 0..1008

    // ---- one-time Whh slice preload into LDS ----
    for (int f = tid; f < 4096; f += NTHR) {
        const int jj = f & 15, kq = f >> 4;
        const float* wp = Whh + (size_t)(kq * 4) * HDIM + jb + jj;
        float4 q;
        q.x = wp[0];
        q.y = wp[HDIM];
        q.z = wp[2 * HDIM];
        q.w = wp[3 * HDIM];
        Wl[kq][jj] = q;
    }

    // finish-phase roles: lanes 0..31 of wave ks handle rows {2ks, 2ks+1}
    const int fr   = (lane >> 4) & 1;
    const int fj   = lane & 15;
    const int frow = rbase + ks * 2 + fr;
    float bias = 0.f;
    if (lane < 32) bias = bhh[jb + fj];
    __syncthreads();

    const size_t BH = (size_t)BATCH * HDIM;

    for (int t = 0; t < T_STEPS; ++t) {
        const float* hp = t ? (outs + (size_t)(t - 1) * BH) : init;
        float* ot = outs + (size_t)t * BH;

        // prefetch xproj for this step's finish (hidden under the k-loop)
        float xp = 0.f;
        if (lane < 32) xp = ot[(size_t)frow * HDIM + jb + fj];

        const float* h0 = hp + (size_t)(rbase + rg * 4) * HDIM + ks * 128;

        float ac0 = 0.f, ac1 = 0.f, ac2 = 0.f, ac3 = 0.f;
#pragma unroll 8
        for (int i = 0; i < 32; ++i) {
            const float4 w  = Wl[(ks << 5) + i][j];
            const float4 v0 = *(const float4*)(h0 + i * 4);
            const float4 v1 = *(const float4*)(h0 + HDIM + i * 4);
            const float4 v2 = *(const float4*)(h0 + 2 * HDIM + i * 4);
            const float4 v3 = *(const float4*)(h0 + 3 * HDIM + i * 4);
            ac0 = fmaf(v0.w, w.w, fmaf(v0.z, w.z, fmaf(v0.y, w.y, fmaf(v0.x, w.x, ac0))));
            ac1 = fmaf(v1.w, w.w, fmaf(v1.z, w.z, fmaf(v1.y, w.y, fmaf(v1.x, w.x, ac1))));
            ac2 = fmaf(v2.w, w.w, fmaf(v2.z, w.z, fmaf(v2.y, w.y, fmaf(v2.x, w.x, ac2))));
            ac3 = fmaf(v3.w, w.w, fmaf(v3.z, w.z, fmaf(v3.y, w.y, fmaf(v3.x, w.x, ac3))));
        }

        const int pb = (ks * 16 + rg * 4) * 17 + j;
        partf[pb]      = ac0;
        partf[pb + 17] = ac1;
        partf[pb + 34] = ac2;
        partf[pb + 51] = ac3;
        __syncthreads();

        if (lane < 32) {
            float s = xp + bias;
            const int rb2 = (ks * 2 + fr) * 17 + fj;
#pragma unroll
            for (int w = 0; w < 8; ++w)
                s += partf[w * 272 + rb2];
            const float hv = fast_tanh(s);
            ot[(size_t)frow * HDIM + jb + fj] = hv;   // h_t lives in outs[t]
            if (t == T_STEPS - 1)
                carry[(size_t)frow * HDIM + jb + fj] = hv;
        }

        if (t < T_STEPS - 1) {
            __syncthreads();   // all waves' stores drained to L2 (vmcnt(0))
            if (tid == 0) {
                // release: buffer_wbl2 flushes this XCD's L2 before the add
                __hip_atomic_fetch_add(bar, 1u, __ATOMIC_RELEASE,
                                       __HIP_MEMORY_SCOPE_AGENT);
                const unsigned tgt = (unsigned)(t + 1) * NWG;
                while (__hip_atomic_load(bar, __ATOMIC_RELAXED,
                                         __HIP_MEMORY_SCOPE_AGENT) < tgt)
                    __builtin_amdgcn_s_sleep(2);
            }
            __syncthreads();
            __threadfence();   // acquire: invalidate L1/L2 before next h read
        }
    }
}

extern "C" void kernel_launch(void* const* d_in, const int* in_sizes, int n_in,
                              void* d_out, int out_size, void* d_ws, size_t ws_size,
                              hipStream_t stream) {
    (void)in_sizes; (void)n_in; (void)out_size;
    const float* init = (const float*)d_in[0];
    const float* xs   = (const float*)d_in[1];
    const float* Wih  = (const float*)d_in[2];
    const float* bih  = (const float*)d_in[3];
    const float* Whh  = (const float*)d_in[4];
    const float* bhh  = (const float*)d_in[5];
    float* out  = (float*)d_out;
    float* outs = out + BATCH * HDIM;   // [T][B][H]

    // barrier counter: workspace if present, else device symbol
    unsigned* bar;
    if (d_ws != nullptr && ws_size >= sizeof(unsigned)) {
        bar = (unsigned*)d_ws;
    } else {
        static void* sym = nullptr;
        if (sym == nullptr) (void)hipGetSymbolAddress(&sym, HIP_SYMBOL(g_bar_fallback));
        bar = (unsigned*)sym;
    }
    hipMemsetAsync(bar, 0, sizeof(unsigned), stream);   // graph-capturable

    // Phase 1: xproj -> outs region of d_out (in-place workspace)
    xproj_gemm<<<dim3(8, 512), 256, 0, stream>>>(xs, Wih, bih, outs);

    // Phase 2: one persistent dispatch, 1024 internal barrier-separated steps
    rnn_scan_persistent<<<dim3(NWG), NTHR, 0, stream>>>(Whh, bhh, init, outs, out, bar);
}

// Round 2
// 12999.991 us; speedup vs baseline: 3.7688x; 3.7688x over previous
//
#include <hip/hip_runtime.h>
#include <hip/hip_bf16.h>

// RNN scan: T=1024, B=64, D_IN=1024, H=1024, fp32.
// out = [carry (64*1024)] ++ [outs (1024*64*1024)]
//
// Phase 1: xproj = xs @ Wih + bih  -> written into outs region of d_out.
// Phase 2: ONE persistent kernel (256 WGs = 1/CU), 1024 internal steps.
//   No cache-maintenance ops (round-1 lesson: RELEASE/threadfence emit
//   buffer_wbl2/buffer_inv -> ~40us/step of serialized L2 walks).
//   Coherence instead via targeted write-through:
//     - h stores: global_store_dword sc0 sc1 (through L2 to MALL).
//     - h loads: plain cached. Safe: outs[t] lines (128B == one 32-col
//       tile row) are only ever pre-cached by their owner (xproj read),
//       and the owner's sc1 store updates that copy in-path. Addresses
//       are time-indexed -> never reused -> no stale reader hits.
//     - barrier: relaxed 2-level atomic counter (no fences).

#define T_STEPS 1024
#define BATCH   64
#define HDIM    1024
#define NWG     256
#define NTHR    512
#define NGRP    8
#define WGS_PER_GRP (NWG / NGRP)

__device__ __align__(128) unsigned g_bar_fallback[32 * (NGRP + 1)];

// ---------- small float4 helpers ----------
__device__ __forceinline__ float4 f4fma(float s, float4 v, float4 a) {
    a.x = fmaf(s, v.x, a.x);
    a.y = fmaf(s, v.y, a.y);
    a.z = fmaf(s, v.z, a.z);
    a.w = fmaf(s, v.w, a.w);
    return a;
}
__device__ __forceinline__ float4 f4add(float4 a, float4 b) {
    return make_float4(a.x + b.x, a.y + b.y, a.z + b.z, a.w + b.w);
}
__device__ __forceinline__ float fast_tanh(float x) {
    float ax = fabsf(x);
    float e  = __expf(2.0f * ax);          // v_exp_f32-based
    float r  = 1.0f - __fdividef(2.0f, e + 1.0f);
    return copysignf(r, x);
}

// ---------- Phase 1: xproj GEMM (fp32, 128x128 tile, 8x8 micro) ----------
// C[r, n] = sum_k A[r,k] * W[k,n] + bias[n];  M=65536, N=K=1024
__global__ __launch_bounds__(256) void xproj_gemm(
    const float* __restrict__ A,     // xs   [65536,1024]
    const float* __restrict__ W,     // Wih  [1024,1024]
    const float* __restrict__ bias,  // bih  [1024]
    float* __restrict__ C)           // outs [65536,1024]
{
    constexpr int K = 1024, N = 1024;
    __shared__ __align__(16) float As[8][132];
    __shared__ __align__(16) float Ws[8][132];

    const int tid = threadIdx.x;
    const int m0 = blockIdx.y * 128;
    const int n0 = blockIdx.x * 128;
    const int tx = tid & 15;          // 0..15 -> col groups
    const int ty = tid >> 4;          // 0..15 -> row groups

    const int arow = tid >> 1;            // 0..127
    const int kq   = (tid & 1) * 4;       // 0 or 4
    const int wrow = tid >> 5;            // 0..7
    const int wcol = (tid & 31) * 4;      // 0..124

    float4 c[2][4][2];
#pragma unroll
    for (int rb = 0; rb < 2; ++rb)
#pragma unroll
        for (int i = 0; i < 4; ++i)
#pragma unroll
            for (int cb = 0; cb < 2; ++cb)
                c[rb][i][cb] = make_float4(0.f, 0.f, 0.f, 0.f);

    for (int k0 = 0; k0 < K; k0 += 8) {
        float4 av = *(const float4*)(A + (size_t)(m0 + arow) * K + k0 + kq);
        float4 wv = *(const float4*)(W + (size_t)(k0 + wrow) * N + n0 + wcol);
        __syncthreads();
        As[kq + 0][arow] = av.x;
        As[kq + 1][arow] = av.y;
        As[kq + 2][arow] = av.z;
        As[kq + 3][arow] = av.w;
        *(float4*)&Ws[wrow][wcol] = wv;
        __syncthreads();
#pragma unroll
        for (int kk = 0; kk < 8; ++kk) {
            float4 a0 = *(const float4*)&As[kk][ty * 4];
            float4 a1 = *(const float4*)&As[kk][64 + ty * 4];
            float4 b0 = *(const float4*)&Ws[kk][tx * 4];
            float4 b1 = *(const float4*)&Ws[kk][64 + tx * 4];
            float a0a[4] = {a0.x, a0.y, a0.z, a0.w};
            float a1a[4] = {a1.x, a1.y, a1.z, a1.w};
#pragma unroll
            for (int i = 0; i < 4; ++i) {
                c[0][i][0] = f4fma(a0a[i], b0, c[0][i][0]);
                c[0][i][1] = f4fma(a0a[i], b1, c[0][i][1]);
                c[1][i][0] = f4fma(a1a[i], b0, c[1][i][0]);
                c[1][i][1] = f4fma(a1a[i], b1, c[1][i][1]);
            }
        }
    }

    float4 bv0 = *(const float4*)(bias + n0 + tx * 4);
    float4 bv1 = *(const float4*)(bias + n0 + 64 + tx * 4);
#pragma unroll
    for (int rb = 0; rb < 2; ++rb)
#pragma unroll
        for (int i = 0; i < 4; ++i) {
            int row = m0 + rb * 64 + ty * 4 + i;
            float* cp = C + (size_t)row * N + n0;
            *(float4*)(cp + tx * 4)      = f4add(c[rb][i][0], bv0);
            *(float4*)(cp + 64 + tx * 4) = f4add(c[rb][i][1], bv1);
        }
}

// ---------- Phase 2: persistent scan kernel ----------
// 256 WGs x 512 threads, 1 WG/CU (LDS 136 KB). WG owns an 8-row x 32-col
// tile of h (32 cols * 4B = 128 B = exactly one cacheline -> tile lines are
// owner-exclusive before the h write). Whh[:, jb..jb+31] lives in LDS as
// k-quads (128 KB), loaded once.
// Per step: 8 waves split K (128 each); lane (rg,j) accumulates 4 rows x
// 1 col; LDS partial reduce; wave ks finishes local row ks (lanes 0..31).
__global__ __launch_bounds__(NTHR) void rnn_scan_persistent(
    const float* __restrict__ Whh,    // [1024,1024]
    const float* __restrict__ bhh,    // [1024]
    const float* __restrict__ init,   // [64,1024]
    float* __restrict__ outs,         // [T][64][1024]  xproj in, h out
    float* __restrict__ carry,        // [64,1024]
    unsigned* __restrict__ bar)       // zeroed per replay; [0]=master, [32*(1+g)]=group g
{
    __shared__ __align__(16) float4 Wl[256][32];          // 128 KB: Wl[kq][j] = W[4kq..4kq+3][jb+j]
    __shared__ __align__(16) float  partf[8 * 2 * 32 * 4]; // 8 KB: [wave][rg][j][c]

    const int tid  = threadIdx.x;
    const int lane = tid & 63;
    const int ks   = tid >> 6;          // wave 0..7: k-slice [ks*128, ks*128+128)
    const int rg   = lane >> 5;         // 0..1: row group (4 rows each)
    const int j    = lane & 31;         // column within tile

    const int l     = blockIdx.x;
    const int rbase = (l >> 5) * 8;     // 8 rows per WG
    const int jb    = (l & 31) * 32;    // 32 cols per WG (128 B aligned)
    const int grp   = l >> 5;           // 8 groups x 32 WGs for the 2-level barrier

    // ---- one-time Whh slice preload into LDS ----
    for (int f = tid; f < 8192; f += NTHR) {
        const int jj = f & 31, kq = f >> 5;
        const float* wp = Whh + (size_t)(kq * 4) * HDIM + jb + jj;
        float4 q;
        q.x = wp[0];
        q.y = wp[HDIM];
        q.z = wp[2 * HDIM];
        q.w = wp[3 * HDIM];
        Wl[kq][jj] = q;
    }

    // finish-phase roles: lanes 0..31 of wave ks handle local row ks
    const int fj   = lane & 31;
    const int frow = rbase + ks;
    float bias = 0.f;
    if (lane < 32) bias = bhh[jb + fj];
    __syncthreads();

    const size_t BH = (size_t)BATCH * HDIM;

    for (int t = 0; t < T_STEPS; ++t) {
        const float* hp = t ? (outs + (size_t)(t - 1) * BH) : init;
        float* ot = outs + (size_t)t * BH;

        // prefetch xproj for this step's finish (own tile line only)
        float xp = 0.f;
        if (lane < 32) xp = ot[(size_t)frow * HDIM + jb + fj];

        const float* h0 = hp + (size_t)(rbase + rg * 4) * HDIM + ks * 128;

        float ac0 = 0.f, ac1 = 0.f, ac2 = 0.f, ac3 = 0.f;
#pragma unroll 8
        for (int i = 0; i < 32; ++i) {
            const float4 w  = Wl[(ks << 5) + i][j];
            const float4 v0 = *(const float4*)(h0 + i * 4);
            const float4 v1 = *(const float4*)(h0 + HDIM + i * 4);
            const float4 v2 = *(const float4*)(h0 + 2 * HDIM + i * 4);
            const float4 v3 = *(const float4*)(h0 + 3 * HDIM + i * 4);
            ac0 = fmaf(v0.w, w.w, fmaf(v0.z, w.z, fmaf(v0.y, w.y, fmaf(v0.x, w.x, ac0))));
            ac1 = fmaf(v1.w, w.w, fmaf(v1.z, w.z, fmaf(v1.y, w.y, fmaf(v1.x, w.x, ac1))));
            ac2 = fmaf(v2.w, w.w, fmaf(v2.z, w.z, fmaf(v2.y, w.y, fmaf(v2.x, w.x, ac2))));
            ac3 = fmaf(v3.w, w.w, fmaf(v3.z, w.z, fmaf(v3.y, w.y, fmaf(v3.x, w.x, ac3))));
        }

        *(float4*)&partf[(((ks << 1) + rg) * 32 + j) << 2] =
            make_float4(ac0, ac1, ac2, ac3);
        __syncthreads();

        if (lane < 32) {
            float s = xp + bias;
            const int rg2 = ks >> 2, c2 = ks & 3;
#pragma unroll
            for (int w = 0; w < 8; ++w)
                s += partf[(((w << 1) + rg2) * 32 + fj) * 4 + c2];
            const float hv = fast_tanh(s);
            float* dst = ot + (size_t)frow * HDIM + jb + fj;
            // write-through to MALL (coherence point) -- no wbl2 ever needed
            asm volatile("global_store_dword %0, %1, off sc0 sc1"
                         :: "v"(dst), "v"(hv) : "memory");
            if (t == T_STEPS - 1)
                carry[(size_t)frow * HDIM + jb + fj] = hv;
        }

        if (t < T_STEPS - 1) {
            __syncthreads();   // vmcnt(0): all waves' sc1 stores MALL-visible
            if (tid == 0) {
                unsigned* gcnt = bar + 32 * (1 + grp);
                unsigned r = __hip_atomic_fetch_add(gcnt, 1u, __ATOMIC_RELAXED,
                                                    __HIP_MEMORY_SCOPE_AGENT);
                if (r == (unsigned)(t + 1) * WGS_PER_GRP - 1u) {
                    __hip_atomic_fetch_add(bar, 1u, __ATOMIC_RELAXED,
                                           __HIP_MEMORY_SCOPE_AGENT);
                }
                const unsigned tgt = (unsigned)(t + 1) * NGRP;
                while (__hip_atomic_load(bar, __ATOMIC_RELAXED,
                                         __HIP_MEMORY_SCOPE_AGENT) < tgt)
                    __builtin_amdgcn_s_sleep(1);
            }
            __syncthreads();
        }
    }
}

extern "C" void kernel_launch(void* const* d_in, const int* in_sizes, int n_in,
                              void* d_out, int out_size, void* d_ws, size_t ws_size,
                              hipStream_t stream) {
    (void)in_sizes; (void)n_in; (void)out_size;
    const float* init = (const float*)d_in[0];
    const float* xs   = (const float*)d_in[1];
    const float* Wih  = (const float*)d_in[2];
    const float* bih  = (const float*)d_in[3];
    const float* Whh  = (const float*)d_in[4];
    const float* bhh  = (const float*)d_in[5];
    float* out  = (float*)d_out;
    float* outs = out + BATCH * HDIM;   // [T][B][H]

    const size_t bar_bytes = 32 * (NGRP + 1) * sizeof(unsigned);
    unsigned* bar;
    if (d_ws != nullptr && ws_size >= bar_bytes) {
        bar = (unsigned*)d_ws;
    } else {
        static void* sym = nullptr;
        if (sym == nullptr) (void)hipGetSymbolAddress(&sym, HIP_SYMBOL(g_bar_fallback));
        bar = (unsigned*)sym;
    }
    hipMemsetAsync(bar, 0, bar_bytes, stream);   // graph-capturable

    // Phase 1: xproj -> outs region of d_out (in-place workspace)
    xproj_gemm<<<dim3(8, 512), 256, 0, stream>>>(xs, Wih, bih, outs);

    // Phase 2: one persistent dispatch, 1024 internal barrier-separated steps
    rnn_scan_persistent<<<dim3(NWG), NTHR, 0, stream>>>(Whh, bhh, init, outs, out, bar);
}